// Round 7
// baseline (550.540 us; speedup 1.0000x reference)
//
#include <hip/hip_runtime.h>
#include <stdint.h>
#include <stddef.h>

// ---------------------------------------------------------------------------
// cseft reassociated (no [H,N,N] scores). 2 launches + 1 memset:
//   L1 prep:  xb=bf16(x), yb=bf16(y), w1t=bf16(W1^T) [1024,512],
//             w23t=bf16([W2|W3]^T) [2048,512]
//   L2 mega (producer/consumer via agent-scope atomics):
//     blocks    0..511 : kvt[2048,4096] = w23t @ yb^T          -> kvflag[by][bx]
//     blocks  512..767 : qb[4096,1024]  = xb @ w1t^T           -> qbrow[my]++
//     blocks  768..895 : Ut tile (s,h)  = sc * V_s,h^T K_s,h   (waits 4 kvflags)
//     blocks 896..1407 : out[4096,2048] = qb @ Ut^T  (fp32)    (waits qbrow, ucnt)
// Deadlock-free: __launch_bounds__(256,3) => 3 blocks/CU => 768 resident slots;
// consumers total 640 < 768, so producers always have slots at any dispatch order.
// N=4096 K=512 H=8 Dh=128 nItem=256 nSet=16 hardcoded.
// ---------------------------------------------------------------------------

typedef short short8 __attribute__((ext_vector_type(8)));
typedef float f32x4 __attribute__((ext_vector_type(4)));

#define AS1 __attribute__((address_space(1)))
#define AS3 __attribute__((address_space(3)))

__device__ __forceinline__ void gl_lds16(const void* g, void* l) {
    __builtin_amdgcn_global_load_lds((AS1 void*)(uintptr_t)g, (AS3 void*)l, 16, 0, 0);
}

__device__ __forceinline__ short f2bf(float f) {
    union { float f; unsigned u; } v; v.f = f;
    unsigned r = v.u + 0x7FFFu + ((v.u >> 16) & 1u);
    return (short)(r >> 16);
}

__device__ __forceinline__ void wait_ge(const int* p, int want) {
    // every thread spins: each gets its own acquire -> airtight ordering
    while (__hip_atomic_load(p, __ATOMIC_ACQUIRE, __HIP_MEMORY_SCOPE_AGENT) < want)
        __builtin_amdgcn_s_sleep(8);
}

// flag layout (ints) at `flags`: [0..511] kvflag[by*32+bx],
// [512..543] qbrow[my], [544..559] ucnt[s]. Zeroed by hipMemsetAsync each call.

// --- prep: 0..1023 x->xb, 1024..2047 y->yb, 2048..3071 W2/W3->w23t (T),
//     3072..3583 W1->w1t (T). 3584 blocks x 256 thr.
__global__ __launch_bounds__(256)
void prep(const float* __restrict__ x, const float* __restrict__ y,
          const float* __restrict__ W1, const float* __restrict__ W2,
          const float* __restrict__ W3, short* __restrict__ xb,
          short* __restrict__ yb, short* __restrict__ w1t,
          short* __restrict__ w23t) {
    const int b = blockIdx.x, tid = threadIdx.x;
    if (b < 2048) {
        const float* in = (b < 1024) ? x : y;
        short* o = (b < 1024) ? xb : yb;
        const int i = (b & 1023) * 256 + tid;
        const float4* p = (const float4*)in + (size_t)i * 2;
        float4 a = p[0], c4 = p[1];
        short8 s8;
        s8[0] = f2bf(a.x);  s8[1] = f2bf(a.y);
        s8[2] = f2bf(a.z);  s8[3] = f2bf(a.w);
        s8[4] = f2bf(c4.x); s8[5] = f2bf(c4.y);
        s8[6] = f2bf(c4.z); s8[7] = f2bf(c4.w);
        *((short8*)o + i) = s8;
        return;
    }
    __shared__ float t[32][33];
    const float* W; short* Wt; int b3;
    if (b < 3072) {
        const int b2 = b - 2048;                 // 0..1023
        const int z = b2 >> 9;                   // 0: W2, 1: W3
        W = z ? W3 : W2;
        Wt = w23t + (size_t)z * 1024 * 512;
        b3 = b2 & 511;
    } else {
        W = W1; Wt = w1t; b3 = b - 3072;         // 0..511
    }
    const int bx = (b3 & 31) * 32, by = (b3 >> 5) * 32;
    const int tx = tid & 31, ty = tid >> 5;
    #pragma unroll
    for (int j = 0; j < 4; ++j)
        t[ty + j * 8][tx] = W[(size_t)(by + ty + j * 8) * 1024 + bx + tx];
    __syncthreads();
    #pragma unroll
    for (int j = 0; j < 4; ++j)
        Wt[(size_t)(bx + ty + j * 8) * 512 + by + tx] = f2bf(t[tx][ty + j * 8]);
}

// --- generic MFMA tile: C[128x128] = A[.,K] * Bt[.,K]^T --------------------
// 4 waves in 2x2; OUTMODE: 0 = f32 store, 1 = bf16 store, 2 = bf16*scale.
template <int OUTMODE>
__device__ __forceinline__
void gemm_tile(const short* __restrict__ A, int lda,
               const short* __restrict__ Bt, int ldb,
               void* __restrict__ Cout, int ldc, int K,
               int bx, int by, float scale, char* smem) {
    short* sA = (short*)smem;                 // [128][32]
    short* sB = (short*)(smem + 8192);        // [128][32]

    const int tid = threadIdx.x;
    const int wave = tid >> 6, lane = tid & 63;
    const int quad = lane >> 4, ml = lane & 15;
    const int m0 = by * 128, n0 = bx * 128;
    const int wm0 = (wave >> 1) * 64, wn0 = (wave & 1) * 64;
    const int srow = lane >> 2, skoff = (lane & 3) * 8;

    f32x4 acc[4][4];
    #pragma unroll
    for (int i = 0; i < 4; ++i)
        #pragma unroll
        for (int j = 0; j < 4; ++j) {
            acc[i][j][0] = 0.f; acc[i][j][1] = 0.f;
            acc[i][j][2] = 0.f; acc[i][j][3] = 0.f;
        }

    for (int kt = 0; kt < K; kt += 32) {
        #pragma unroll
        for (int ci = 0; ci < 4; ++ci) {
            const int c = wave + ci * 4;
            if (c < 8)
                gl_lds16(A + (size_t)(m0 + c * 16 + srow) * lda + kt + skoff,
                         (char*)sA + c * 1024 + lane * 16);
            else
                gl_lds16(Bt + (size_t)(n0 + (c - 8) * 16 + srow) * ldb + kt + skoff,
                         (char*)sB + (c - 8) * 1024 + lane * 16);
        }
        __syncthreads();   // drains vmcnt for global_load_lds

        short8 af[4], bfr[4];
        #pragma unroll
        for (int mt = 0; mt < 4; ++mt)
            af[mt] = *(const short8*)(sA + (wm0 + mt * 16 + ml) * 32 + quad * 8);
        #pragma unroll
        for (int nt = 0; nt < 4; ++nt)
            bfr[nt] = *(const short8*)(sB + (wn0 + nt * 16 + ml) * 32 + quad * 8);

        #pragma unroll
        for (int mt = 0; mt < 4; ++mt)
            #pragma unroll
            for (int nt = 0; nt < 4; ++nt)
                acc[mt][nt] = __builtin_amdgcn_mfma_f32_16x16x32_bf16(
                    af[mt], bfr[nt], acc[mt][nt], 0, 0, 0);
        __syncthreads();
    }

    // C/D layout: col = lane&15, row = quad*4 + reg
    #pragma unroll
    for (int mt = 0; mt < 4; ++mt)
        #pragma unroll
        for (int nt = 0; nt < 4; ++nt) {
            const int col = n0 + wn0 + nt * 16 + ml;
            #pragma unroll
            for (int r = 0; r < 4; ++r) {
                const int row = m0 + wm0 + mt * 16 + quad * 4 + r;
                float v = acc[mt][nt][r];
                if (OUTMODE == 2) v *= scale;
                if (OUTMODE == 0)
                    ((float*)Cout)[(size_t)row * ldc + col] = v;
                else
                    ((short*)Cout)[(size_t)row * ldc + col] = f2bf(v);
            }
        }
}

__global__ __launch_bounds__(256, 3)
void mega(const short* __restrict__ xb, const short* __restrict__ yb,
          const short* __restrict__ w1t, const short* __restrict__ w23t,
          const float* __restrict__ cw, short* __restrict__ kvt,
          short* __restrict__ qb, short* __restrict__ Ut,
          float* __restrict__ out, int* __restrict__ flags) {
    __shared__ char smem[16384];
    const int b = blockIdx.x, tid = threadIdx.x;

    if (b < 512) {
        // kvt[2048,4096] = w23t @ yb^T : m-tiles(channels) 16, n-tiles(items) 32
        const int by = b >> 5, bx = b & 31;
        gemm_tile<1>(w23t, 512, yb, 512, kvt, 4096, 512, bx, by, 1.f, smem);
        __threadfence();                     // make stores agent-visible
        __syncthreads();
        if (tid == 0)
            __hip_atomic_store(&flags[(by << 5) | bx], 1,
                               __ATOMIC_RELEASE, __HIP_MEMORY_SCOPE_AGENT);
    } else if (b < 768) {
        // qb[4096,1024] = xb @ w1t^T : m-tiles 32, n-tiles 8
        const int b2 = b - 512;
        const int my = b2 >> 3, nx = b2 & 7;
        gemm_tile<1>(xb, 512, w1t, 512, qb, 1024, 512, nx, my, 1.f, smem);
        __threadfence();
        __syncthreads();
        if (tid == 0)
            __hip_atomic_fetch_add(&flags[512 + my], 1,
                                   __ATOMIC_RELEASE, __HIP_MEMORY_SCOPE_AGENT);
    } else if (b < 896) {
        // build_u tile (s,h): Ut[s*128..][h*128..] = sc * V_s,h^T @ K_s,h
        const int b2 = b - 768;
        const int s = b2 & 15, h = b2 >> 4;
        wait_ge(&flags[(h << 5) | (2 * s)], 1);
        wait_ge(&flags[(h << 5) | (2 * s + 1)], 1);
        wait_ge(&flags[((8 + h) << 5) | (2 * s)], 1);
        wait_ge(&flags[((8 + h) << 5) | (2 * s + 1)], 1);
        const float scale = cw[h] * (0.08838834764831845f / 256.0f);
        gemm_tile<2>(kvt + (size_t)(1024 + h * 128) * 4096 + s * 256, 4096,  // V
                     kvt + (size_t)(h * 128) * 4096 + s * 256, 4096,         // K
                     Ut + (size_t)(s * 128) * 1024 + h * 128, 1024, 256,
                     0, 0, scale, smem);
        __threadfence();
        __syncthreads();
        if (tid == 0)
            __hip_atomic_fetch_add(&flags[544 + s], 1,
                                   __ATOMIC_RELEASE, __HIP_MEMORY_SCOPE_AGENT);
    } else {
        // out[4096,2048] = qb @ Ut^T, fp32: tile (s = n-tile, my = m-tile)
        const int b2 = b - 896;
        const int s = b2 & 15, my = b2 >> 4;
        wait_ge(&flags[512 + my], 8);   // all 8 qb column-tiles of row-strip my
        wait_ge(&flags[544 + s], 8);    // all 8 head-tiles of Ut row-strip s
        gemm_tile<0>(qb, 1024, Ut, 1024, out, 2048, 1024, s, my, 1.f, smem);
    }
}

extern "C" void kernel_launch(void* const* d_in, const int* in_sizes, int n_in,
                              void* d_out, int out_size, void* d_ws, size_t ws_size,
                              hipStream_t stream) {
    const float* x  = (const float*)d_in[0];  // [4096, 512]
    const float* y  = (const float*)d_in[1];  // [4096, 512]
    const float* W1 = (const float*)d_in[2];  // [512, 1024]
    const float* W2 = (const float*)d_in[3];
    const float* W3 = (const float*)d_in[4];
    const float* cw = (const float*)d_in[5];  // [8]
    float* out = (float*)d_out;               // [4096, 16, 128]

    char* ws = (char*)d_ws;
    short* xb   = (short*)(ws);                        //  4 MB
    short* yb   = (short*)(ws + (4u << 20));           //  4 MB
    short* w1t  = (short*)(ws + (8u << 20));           //  1 MB
    short* w23t = (short*)(ws + (9u << 20));           //  2 MB
    short* kvt  = (short*)(ws + (11u << 20));          // 16 MB
    short* qb   = (short*)(ws + (27u << 20));          //  8 MB
    short* Ut   = (short*)(ws + (35u << 20));          //  4 MB
    int*  flags = (int*)(ws + (48u << 20));            // 560 ints

    hipMemsetAsync(flags, 0, 560 * sizeof(int), stream);
    prep<<<3584, 256, 0, stream>>>(x, y, W1, W2, W3, xb, yb, w1t, w23t);
    mega<<<1408, 256, 0, stream>>>(xb, yb, w1t, w23t, cw, kvt, qb, Ut, out, flags);
}

// Round 8
// 147.924 us; speedup vs baseline: 3.7218x; 3.7218x over previous
//
#include <hip/hip_runtime.h>
#include <stdint.h>
#include <stddef.h>

// ---------------------------------------------------------------------------
// cseft reassociated (no [H,N,N] scores). 4 launches:
//   1. prep:  xb=bf16(x), yb=bf16(y), w1t=bf16(W1^T) [1024,512],
//             w23t=bf16([W2|W3]^T) [2048,512]
//   2. stageB: kvt[2048,4096] = w23t @ yb^T  (rows 0..1023 k-ch, 1024.. v-ch)
//              qb [4096,1024] = xb @ w1t^T        (both MFMA, bf16 out)
//   3. build_u (MFMA): Ut[s*128+d][h*128+dp] =
//              cw[h]*sc * sum_i kvt[1024+h*128+d][s*256+i]*kvt[h*128+dp][s*256+i]
//   4. out[4096,2048] = qb @ Ut^T  (MFMA, fp32 out)
// GEMM tile: BK=64 (one barrier per 64 k — halves barrier count vs BK=32),
// 128x128 (or 64x128) tiles, 4 waves, global_load_lds width-16 staging.
// R7 lesson: cross-block spin-flag sync is pathological (488us, MfmaUtil 2.5%)
// — stages stay as separate launches.
// N=4096 K=512 H=8 Dh=128 nItem=256 nSet=16 hardcoded.
// ---------------------------------------------------------------------------

typedef short short8 __attribute__((ext_vector_type(8)));
typedef float f32x4 __attribute__((ext_vector_type(4)));

#define AS1 __attribute__((address_space(1)))
#define AS3 __attribute__((address_space(3)))

__device__ __forceinline__ void gl_lds16(const void* g, void* l) {
    __builtin_amdgcn_global_load_lds((AS1 void*)(uintptr_t)g, (AS3 void*)l, 16, 0, 0);
}

__device__ __forceinline__ short f2bf(float f) {
    union { float f; unsigned u; } v; v.f = f;
    unsigned r = v.u + 0x7FFFu + ((v.u >> 16) & 1u);
    return (short)(r >> 16);
}

// --- prep: 0..1023 x->xb, 1024..2047 y->yb, 2048..3071 W2/W3->w23t (T),
//     3072..3583 W1->w1t (T). 3584 blocks x 256 thr.
__global__ __launch_bounds__(256)
void prep(const float* __restrict__ x, const float* __restrict__ y,
          const float* __restrict__ W1, const float* __restrict__ W2,
          const float* __restrict__ W3, short* __restrict__ xb,
          short* __restrict__ yb, short* __restrict__ w1t,
          short* __restrict__ w23t) {
    const int b = blockIdx.x, tid = threadIdx.x;
    if (b < 2048) {
        const float* in = (b < 1024) ? x : y;
        short* o = (b < 1024) ? xb : yb;
        const int i = (b & 1023) * 256 + tid;
        const float4* p = (const float4*)in + (size_t)i * 2;
        float4 a = p[0], c4 = p[1];
        short8 s8;
        s8[0] = f2bf(a.x);  s8[1] = f2bf(a.y);
        s8[2] = f2bf(a.z);  s8[3] = f2bf(a.w);
        s8[4] = f2bf(c4.x); s8[5] = f2bf(c4.y);
        s8[6] = f2bf(c4.z); s8[7] = f2bf(c4.w);
        *((short8*)o + i) = s8;
        return;
    }
    __shared__ float t[32][33];
    const float* W; short* Wt; int b3;
    if (b < 3072) {
        const int b2 = b - 2048;                 // 0..1023
        const int z = b2 >> 9;                   // 0: W2, 1: W3
        W = z ? W3 : W2;
        Wt = w23t + (size_t)z * 1024 * 512;
        b3 = b2 & 511;
    } else {
        W = W1; Wt = w1t; b3 = b - 3072;         // 0..511
    }
    const int bx = (b3 & 31) * 32, by = (b3 >> 5) * 32;
    const int tx = tid & 31, ty = tid >> 5;
    #pragma unroll
    for (int j = 0; j < 4; ++j)
        t[ty + j * 8][tx] = W[(size_t)(by + ty + j * 8) * 1024 + bx + tx];
    __syncthreads();
    #pragma unroll
    for (int j = 0; j < 4; ++j)
        Wt[(size_t)(bx + ty + j * 8) * 512 + by + tx] = f2bf(t[tx][ty + j * 8]);
}

// --- MFMA tile: C[BM x 128] = A[.,K] * Bt[.,K]^T, BK=64 --------------------
// 4 waves in 2x2; OUTMODE: 0 = f32 store, 1 = bf16 store, 2 = bf16*scale.
// BM in {64,128}. LDS: BM*128 + 16384 bytes.
template <int BM, int OUTMODE>
__device__ __forceinline__
void gemm_tile(const short* __restrict__ A, int lda,
               const short* __restrict__ Bt, int ldb,
               void* __restrict__ Cout, int ldc, int K,
               int bx, int by, float scale) {
    constexpr int MT = BM / 32;                // m-frags per wave (2 or 4)
    constexpr int NCA = BM / 8, NCB = 16, NC = NCA + NCB;   // 8-row chunks
    __shared__ short sA[BM * 64];
    __shared__ short sB[128 * 64];

    const int tid = threadIdx.x;
    const int wave = tid >> 6, lane = tid & 63;
    const int quad = lane >> 4, ml = lane & 15;
    const int m0 = by * BM, n0 = bx * 128;
    const int wm0 = (wave >> 1) * (BM / 2), wn0 = (wave & 1) * 64;
    const int srow = lane >> 3, skoff = (lane & 7) * 8;   // 8 rows/chunk, 64-short rows

    f32x4 acc[MT][4];
    #pragma unroll
    for (int i = 0; i < MT; ++i)
        #pragma unroll
        for (int j = 0; j < 4; ++j) {
            acc[i][j][0] = 0.f; acc[i][j][1] = 0.f;
            acc[i][j][2] = 0.f; acc[i][j][3] = 0.f;
        }

    for (int kt = 0; kt < K; kt += 64) {
        #pragma unroll
        for (int ci = 0; ci < NC / 4; ++ci) {
            const int c = wave + ci * 4;
            if (c < NCA)
                gl_lds16(A + (size_t)(m0 + c * 8 + srow) * lda + kt + skoff,
                         (char*)sA + c * 1024 + lane * 16);
            else
                gl_lds16(Bt + (size_t)(n0 + (c - NCA) * 8 + srow) * ldb + kt + skoff,
                         (char*)sB + (c - NCA) * 1024 + lane * 16);
        }
        __syncthreads();   // drains vmcnt for global_load_lds

        #pragma unroll
        for (int ks = 0; ks < 2; ++ks) {
            short8 af[MT], bfr[4];
            #pragma unroll
            for (int mt = 0; mt < MT; ++mt)
                af[mt] = *(const short8*)(sA + (wm0 + mt * 16 + ml) * 64
                                          + ks * 32 + quad * 8);
            #pragma unroll
            for (int nt = 0; nt < 4; ++nt)
                bfr[nt] = *(const short8*)(sB + (wn0 + nt * 16 + ml) * 64
                                           + ks * 32 + quad * 8);
            #pragma unroll
            for (int mt = 0; mt < MT; ++mt)
                #pragma unroll
                for (int nt = 0; nt < 4; ++nt)
                    acc[mt][nt] = __builtin_amdgcn_mfma_f32_16x16x32_bf16(
                        af[mt], bfr[nt], acc[mt][nt], 0, 0, 0);
        }
        __syncthreads();
    }

    // C/D layout: col = lane&15, row = quad*4 + reg
    #pragma unroll
    for (int mt = 0; mt < MT; ++mt)
        #pragma unroll
        for (int nt = 0; nt < 4; ++nt) {
            const int col = n0 + wn0 + nt * 16 + ml;
            #pragma unroll
            for (int r = 0; r < 4; ++r) {
                const int row = m0 + wm0 + mt * 16 + quad * 4 + r;
                float v = acc[mt][nt][r];
                if (OUTMODE == 2) v *= scale;
                if (OUTMODE == 0)
                    ((float*)Cout)[(size_t)row * ldc + col] = v;
                else
                    ((short*)Cout)[(size_t)row * ldc + col] = f2bf(v);
            }
        }
}

// stage B: blocks 0..511 kvt tiles, 512..767 qb tiles.
__global__ __launch_bounds__(256)
void stage_b(const short* __restrict__ yb, const short* __restrict__ w23t,
             const short* __restrict__ xb, const short* __restrict__ w1t,
             short* __restrict__ kvt, short* __restrict__ qb) {
    const int b = blockIdx.x;
    if (b < 512) {
        // kvt[2048,4096] = w23t @ yb^T : m-tiles 16, n-tiles 32
        gemm_tile<128, 1>(w23t, 512, yb, 512, kvt, 4096, 512,
                          b & 31, b >> 5, 1.f);
    } else {
        // qb[4096,1024] = xb @ w1t^T : m-tiles 32, n-tiles 8
        const int b2 = b - 512;
        gemm_tile<128, 1>(xb, 512, w1t, 512, qb, 1024, 512,
                          b2 & 7, b2 >> 3, 1.f);
    }
}

// build_u: grid (16,8,2); 64x128 tile: Ut rows (s*128+half*64 ..+64),
// cols (h*128 ..+128) = scale * V_rows @ K_rows^T, K=256.
__global__ __launch_bounds__(256)
void build_u(const short* __restrict__ kvt, const float* __restrict__ cw,
             short* __restrict__ Ut) {
    const int s = blockIdx.x, h = blockIdx.y, half = blockIdx.z;
    const float scale = cw[h] * (0.08838834764831845f / 256.0f);
    gemm_tile<64, 2>(
        kvt + (size_t)(1024 + h * 128 + half * 64) * 4096 + s * 256, 4096,  // V
        kvt + (size_t)(h * 128) * 4096 + s * 256, 4096,                     // K
        Ut + (size_t)(s * 128 + half * 64) * 1024 + h * 128, 1024, 256,
        0, 0, scale);
}

// out[4096,2048] = qb @ Ut^T, fp32. grid (16,32).
__global__ __launch_bounds__(256)
void gemm_out(const short* __restrict__ qb, const short* __restrict__ Ut,
              float* __restrict__ out) {
    gemm_tile<128, 0>(qb, 1024, Ut, 1024, out, 2048, 1024,
                      blockIdx.x, blockIdx.y, 1.f);
}

extern "C" void kernel_launch(void* const* d_in, const int* in_sizes, int n_in,
                              void* d_out, int out_size, void* d_ws, size_t ws_size,
                              hipStream_t stream) {
    const float* x  = (const float*)d_in[0];  // [4096, 512]
    const float* y  = (const float*)d_in[1];  // [4096, 512]
    const float* W1 = (const float*)d_in[2];  // [512, 1024]
    const float* W2 = (const float*)d_in[3];
    const float* W3 = (const float*)d_in[4];
    const float* cw = (const float*)d_in[5];  // [8]
    float* out = (float*)d_out;               // [4096, 16, 128]

    short* xb   = (short*)d_ws;                       // 4096*512
    short* yb   = xb   + (size_t)4096 * 512;          // 4096*512
    short* w1t  = yb   + (size_t)4096 * 512;          // 1024*512 (transposed)
    short* w23t = w1t  + (size_t)1024 * 512;          // 2048*512 (transposed)
    short* kvt  = w23t + (size_t)2048 * 512;          // 2048*4096
    short* qb   = kvt  + (size_t)2048 * 4096;         // 4096*1024
    short* Ut   = qb   + (size_t)4096 * 1024;         // 2048*1024

    prep<<<3584, 256, 0, stream>>>(x, y, W1, W2, W3, xb, yb, w1t, w23t);
    stage_b<<<768, 256, 0, stream>>>(yb, w23t, xb, w1t, kvt, qb);
    build_u<<<dim3(16, 8, 2), 256, 0, stream>>>(kvt, cw, Ut);
    gemm_out<<<dim3(16, 32), 256, 0, stream>>>(qb, Ut, out);
}

// Round 9
// 145.237 us; speedup vs baseline: 3.7906x; 1.0185x over previous
//
#include <hip/hip_runtime.h>
#include <stdint.h>
#include <stddef.h>

// ---------------------------------------------------------------------------
// cseft reassociated (no [H,N,N] scores). 4 launches:
//   1. prep:  xb=bf16(x), yb=bf16(y), w1t=bf16(W1^T) [1024,512],
//             w23t=bf16([W2|W3]^T) [2048,512]
//   2. stageB: kvt[2048,4096] = w23t @ yb^T  (rows 0..1023 k-ch, 1024.. v-ch)
//              qb [4096,1024] = xb @ w1t^T        (both MFMA, bf16 out)
//   3. build_u (MFMA): Ut[s*128+d][h*128+dp] =
//              cw[h]*sc * sum_i kvt[1024+h*128+d][s*256+i]*kvt[h*128+dp][s*256+i]
//   4. out[4096,2048] = qb @ Ut^T  (MFMA, fp32 out)
// GEMM tile: BK=32 (R8 showed BK=64 regresses: LDS doubling cuts occupancy),
// v_mfma_f32_32x32x16_bf16 (2382 TF ceiling vs 2075 for 16x16x32; half the
// ds_read count). R7 lesson: no cross-block spin sync.
// N=4096 K=512 H=8 Dh=128 nItem=256 nSet=16 hardcoded.
// ---------------------------------------------------------------------------

typedef short short8 __attribute__((ext_vector_type(8)));
typedef float f32x16 __attribute__((ext_vector_type(16)));

#define AS1 __attribute__((address_space(1)))
#define AS3 __attribute__((address_space(3)))

__device__ __forceinline__ void gl_lds16(const void* g, void* l) {
    __builtin_amdgcn_global_load_lds((AS1 void*)(uintptr_t)g, (AS3 void*)l, 16, 0, 0);
}

__device__ __forceinline__ short f2bf(float f) {
    union { float f; unsigned u; } v; v.f = f;
    unsigned r = v.u + 0x7FFFu + ((v.u >> 16) & 1u);
    return (short)(r >> 16);
}

// --- prep: 0..1023 x->xb, 1024..2047 y->yb, 2048..3071 W2/W3->w23t (T),
//     3072..3583 W1->w1t (T). 3584 blocks x 256 thr.
__global__ __launch_bounds__(256)
void prep(const float* __restrict__ x, const float* __restrict__ y,
          const float* __restrict__ W1, const float* __restrict__ W2,
          const float* __restrict__ W3, short* __restrict__ xb,
          short* __restrict__ yb, short* __restrict__ w1t,
          short* __restrict__ w23t) {
    const int b = blockIdx.x, tid = threadIdx.x;
    if (b < 2048) {
        const float* in = (b < 1024) ? x : y;
        short* o = (b < 1024) ? xb : yb;
        const int i = (b & 1023) * 256 + tid;
        const float4* p = (const float4*)in + (size_t)i * 2;
        float4 a = p[0], c4 = p[1];
        short8 s8;
        s8[0] = f2bf(a.x);  s8[1] = f2bf(a.y);
        s8[2] = f2bf(a.z);  s8[3] = f2bf(a.w);
        s8[4] = f2bf(c4.x); s8[5] = f2bf(c4.y);
        s8[6] = f2bf(c4.z); s8[7] = f2bf(c4.w);
        *((short8*)o + i) = s8;
        return;
    }
    __shared__ float t[32][33];
    const float* W; short* Wt; int b3;
    if (b < 3072) {
        const int b2 = b - 2048;                 // 0..1023
        const int z = b2 >> 9;                   // 0: W2, 1: W3
        W = z ? W3 : W2;
        Wt = w23t + (size_t)z * 1024 * 512;
        b3 = b2 & 511;
    } else {
        W = W1; Wt = w1t; b3 = b - 3072;         // 0..511
    }
    const int bx = (b3 & 31) * 32, by = (b3 >> 5) * 32;
    const int tx = tid & 31, ty = tid >> 5;
    #pragma unroll
    for (int j = 0; j < 4; ++j)
        t[ty + j * 8][tx] = W[(size_t)(by + ty + j * 8) * 1024 + bx + tx];
    __syncthreads();
    #pragma unroll
    for (int j = 0; j < 4; ++j)
        Wt[(size_t)(bx + ty + j * 8) * 512 + by + tx] = f2bf(t[tx][ty + j * 8]);
}

// --- MFMA tile: C[BM x 128] = A[.,K] * Bt[.,K]^T, BK=32, 32x32x16 MFMA ----
// 4 waves in 2x2 (wave-tile BM/2 x 64). OUTMODE: 0=f32, 1=bf16, 2=bf16*scale.
// BM in {64,128}. LDS: (BM+128)*64 bytes.
template <int BM, int OUTMODE>
__device__ __forceinline__
void gemm_tile(const short* __restrict__ A, int lda,
               const short* __restrict__ Bt, int ldb,
               void* __restrict__ Cout, int ldc, int K,
               int bx, int by, float scale) {
    constexpr int MB = BM / 64;                // 32x32 blocks per wave in m
    constexpr int NCA = BM / 16, NC = NCA + 8; // 16-row staging chunks
    __shared__ short sA[BM * 32];
    __shared__ short sB[128 * 32];

    const int tid = threadIdx.x;
    const int wave = tid >> 6, lane = tid & 63;
    const int row32 = lane & 31, khalf = lane >> 5;
    const int m0 = by * BM, n0 = bx * 128;
    const int wm0 = (wave >> 1) * (BM / 2), wn0 = (wave & 1) * 64;
    const int srow = lane >> 2, skoff = (lane & 3) * 8;

    f32x16 acc[MB][2];
    #pragma unroll
    for (int i = 0; i < MB; ++i)
        #pragma unroll
        for (int j = 0; j < 2; ++j)
            #pragma unroll
            for (int e = 0; e < 16; ++e) acc[i][j][e] = 0.f;

    for (int kt = 0; kt < K; kt += 32) {
        #pragma unroll
        for (int ci = 0; ci < NC / 4; ++ci) {
            const int c = wave + ci * 4;
            if (c < NCA)
                gl_lds16(A + (size_t)(m0 + c * 16 + srow) * lda + kt + skoff,
                         (char*)sA + c * 1024 + lane * 16);
            else
                gl_lds16(Bt + (size_t)(n0 + (c - NCA) * 16 + srow) * ldb + kt + skoff,
                         (char*)sB + (c - NCA) * 1024 + lane * 16);
        }
        __syncthreads();   // drains vmcnt for global_load_lds

        // A/B fragment: elem j of lane -> k = kh*16 + khalf*8 + j
        short8 af[MB][2], bfr[2][2];
        #pragma unroll
        for (int mb = 0; mb < MB; ++mb)
            #pragma unroll
            for (int kh = 0; kh < 2; ++kh)
                af[mb][kh] = *(const short8*)(sA + (wm0 + mb * 32 + row32) * 32
                                              + kh * 16 + khalf * 8);
        #pragma unroll
        for (int nb = 0; nb < 2; ++nb)
            #pragma unroll
            for (int kh = 0; kh < 2; ++kh)
                bfr[nb][kh] = *(const short8*)(sB + (wn0 + nb * 32 + row32) * 32
                                               + kh * 16 + khalf * 8);
        #pragma unroll
        for (int mb = 0; mb < MB; ++mb)
            #pragma unroll
            for (int nb = 0; nb < 2; ++nb)
                #pragma unroll
                for (int kh = 0; kh < 2; ++kh)
                    acc[mb][nb] = __builtin_amdgcn_mfma_f32_32x32x16_bf16(
                        af[mb][kh], bfr[nb][kh], acc[mb][nb], 0, 0, 0);
        __syncthreads();
    }

    // C/D layout (m74/m101): col = lane&31, row = (reg&3) + 8*(reg>>2) + 4*(lane>>5)
    #pragma unroll
    for (int mb = 0; mb < MB; ++mb)
        #pragma unroll
        for (int nb = 0; nb < 2; ++nb) {
            const int col = n0 + wn0 + nb * 32 + row32;
            #pragma unroll
            for (int reg = 0; reg < 16; ++reg) {
                const int row = m0 + wm0 + mb * 32
                              + (reg & 3) + 8 * (reg >> 2) + 4 * khalf;
                float v = acc[mb][nb][reg];
                if (OUTMODE == 2) v *= scale;
                if (OUTMODE == 0)
                    ((float*)Cout)[(size_t)row * ldc + col] = v;
                else
                    ((short*)Cout)[(size_t)row * ldc + col] = f2bf(v);
            }
        }
}

// stage B: blocks 0..511 kvt tiles, 512..767 qb tiles.
__global__ __launch_bounds__(256)
void stage_b(const short* __restrict__ yb, const short* __restrict__ w23t,
             const short* __restrict__ xb, const short* __restrict__ w1t,
             short* __restrict__ kvt, short* __restrict__ qb) {
    const int b = blockIdx.x;
    if (b < 512) {
        // kvt[2048,4096] = w23t @ yb^T : m-tiles 16, n-tiles 32
        gemm_tile<128, 1>(w23t, 512, yb, 512, kvt, 4096, 512,
                          b & 31, b >> 5, 1.f);
    } else {
        // qb[4096,1024] = xb @ w1t^T : m-tiles 32, n-tiles 8
        const int b2 = b - 512;
        gemm_tile<128, 1>(xb, 512, w1t, 512, qb, 1024, 512,
                          b2 & 7, b2 >> 3, 1.f);
    }
}

// build_u: grid (16,8,2); 64x128 tile: Ut rows (s*128+half*64 ..+64),
// cols (h*128 ..+128) = scale * V_rows @ K_rows^T, K=256.
__global__ __launch_bounds__(256)
void build_u(const short* __restrict__ kvt, const float* __restrict__ cw,
             short* __restrict__ Ut) {
    const int s = blockIdx.x, h = blockIdx.y, half = blockIdx.z;
    const float scale = cw[h] * (0.08838834764831845f / 256.0f);
    gemm_tile<64, 2>(
        kvt + (size_t)(1024 + h * 128 + half * 64) * 4096 + s * 256, 4096,  // V
        kvt + (size_t)(h * 128) * 4096 + s * 256, 4096,                     // K
        Ut + (size_t)(s * 128 + half * 64) * 1024 + h * 128, 1024, 256,
        0, 0, scale);
}

// out[4096,2048] = qb @ Ut^T, fp32. grid (16,32).
__global__ __launch_bounds__(256)
void gemm_out(const short* __restrict__ qb, const short* __restrict__ Ut,
              float* __restrict__ out) {
    gemm_tile<128, 0>(qb, 1024, Ut, 1024, out, 2048, 1024,
                      blockIdx.x, blockIdx.y, 1.f);
}

extern "C" void kernel_launch(void* const* d_in, const int* in_sizes, int n_in,
                              void* d_out, int out_size, void* d_ws, size_t ws_size,
                              hipStream_t stream) {
    const float* x  = (const float*)d_in[0];  // [4096, 512]
    const float* y  = (const float*)d_in[1];  // [4096, 512]
    const float* W1 = (const float*)d_in[2];  // [512, 1024]
    const float* W2 = (const float*)d_in[3];
    const float* W3 = (const float*)d_in[4];
    const float* cw = (const float*)d_in[5];  // [8]
    float* out = (float*)d_out;               // [4096, 16, 128]

    short* xb   = (short*)d_ws;                       // 4096*512
    short* yb   = xb   + (size_t)4096 * 512;          // 4096*512
    short* w1t  = yb   + (size_t)4096 * 512;          // 1024*512 (transposed)
    short* w23t = w1t  + (size_t)1024 * 512;          // 2048*512 (transposed)
    short* kvt  = w23t + (size_t)2048 * 512;          // 2048*4096
    short* qb   = kvt  + (size_t)2048 * 4096;         // 4096*1024
    short* Ut   = qb   + (size_t)4096 * 1024;         // 2048*1024

    prep<<<3584, 256, 0, stream>>>(x, y, W1, W2, W3, xb, yb, w1t, w23t);
    stage_b<<<768, 256, 0, stream>>>(yb, w23t, xb, w1t, kvt, qb);
    build_u<<<dim3(16, 8, 2), 256, 0, stream>>>(kvt, cw, Ut);
    gemm_out<<<dim3(16, 32), 256, 0, stream>>>(qb, Ut, out);
}